// Round 1
// baseline (1180.912 us; speedup 1.0000x reference)
//
#include <hip/hip_runtime.h>

#define INC 5
#define H1C 16
#define H2C 32
#define KCL 256

// ---------------------------------------------------------------------------
// Detect whether edge_index is int64 (JAX x64 on) or int32 (default).
// If int64, the odd 32-bit words (high halves) are all zero (values < 2^31).
// Probability of 16 random int32 node ids all being 0 is ~1e-80.
__global__ void k_detect(const unsigned int* __restrict__ ei, int* __restrict__ flag) {
    if (blockIdx.x == 0 && threadIdx.x == 0) {
        int is64 = 1;
        for (int i = 1; i < 32; i += 2)
            if (ei[i] != 0u) is64 = 0;
        *flag = is64;
    }
}

// ---------------------------------------------------------------------------
// Per-edge scatter: xsum[dst][0..4] += x[src][0..4]; xsum[dst][5] += 1 (degree)
__global__ void k_edge(const unsigned int* __restrict__ ei, const float* __restrict__ x,
                       float* __restrict__ xsum, const int* __restrict__ flag, int E) {
    int e = blockIdx.x * blockDim.x + threadIdx.x;
    if (e >= E) return;
    const int is64 = *flag;  // uniform, cached
    int src, dst;
    if (is64) {
        src = (int)ei[(size_t)2 * e];
        dst = (int)ei[(size_t)2 * ((size_t)E + (size_t)e)];
    } else {
        src = (int)ei[e];
        dst = (int)ei[(size_t)E + (size_t)e];
    }
    const float* xr = x + (size_t)src * INC;
    float* o = xsum + (size_t)dst * 6;
    atomicAdd(o + 0, xr[0]);
    atomicAdd(o + 1, xr[1]);
    atomicAdd(o + 2, xr[2]);
    atomicAdd(o + 3, xr[3]);
    atomicAdd(o + 4, xr[4]);
    atomicAdd(o + 5, 1.0f);
}

// ---------------------------------------------------------------------------
// Per-node: h[n] = relu( (xsum[n,0:5]/max(deg,1)) @ W1 + x[n] @ root1 + b1 )
// (relu(leaky(relu(v))) == relu(v))
__global__ void k_node(const float* __restrict__ x, const float* __restrict__ xsum,
                       const float* __restrict__ W1, const float* __restrict__ root1,
                       const float* __restrict__ b1, float* __restrict__ h, int N) {
    int n = blockIdx.x * blockDim.x + threadIdx.x;
    if (n >= N) return;
    const float inv = 1.0f / fmaxf(xsum[(size_t)n * 6 + 5], 1.0f);
    float xs[INC], xv[INC];
#pragma unroll
    for (int c = 0; c < INC; c++) {
        xs[c] = xsum[(size_t)n * 6 + c] * inv;
        xv[c] = x[(size_t)n * INC + c];
    }
    float hv[H1C];
#pragma unroll
    for (int j = 0; j < H1C; j++) {
        float v = b1[j];
#pragma unroll
        for (int c = 0; c < INC; c++)
            v = fmaf(xs[c], W1[c * H1C + j], fmaf(xv[c], root1[c * H1C + j], v));
        hv[j] = fmaxf(v, 0.0f);
    }
    float4* hp = (float4*)(h + (size_t)n * H1C);
#pragma unroll
    for (int q = 0; q < 4; q++)
        hp[q] = make_float4(hv[4 * q], hv[4 * q + 1], hv[4 * q + 2], hv[4 * q + 3]);
}

// ---------------------------------------------------------------------------
// xp[k][j] += sum_n pos[n][k] * h[n][j]   (256 x N x 16 tall-skinny GEMM)
// 1024 threads: k = tid&255 (pos column), sub = tid>>8 walks nodes stride 4.
// h row is wave-uniform -> scalar loads; pos load coalesced.
__global__ __launch_bounds__(1024) void k_pool(const float* __restrict__ pos,
                                               const float* __restrict__ h,
                                               float* __restrict__ xp, int N, int nb) {
    __shared__ float red[KCL * (H1C + 1)];  // +1 pad: LDS bank spread
    const int tid = threadIdx.x;
    const int k = tid & (KCL - 1);
    const int sub = tid >> 8;  // 0..3, uniform per wave
    const int chunk = (N + nb - 1) / nb;
    const int n0 = blockIdx.x * chunk;
    const int n1 = min(n0 + chunk, N);

    float acc[H1C];
#pragma unroll
    for (int j = 0; j < H1C; j++) acc[j] = 0.0f;

    for (int n = n0 + sub; n < n1; n += 4) {
        const float p = pos[(size_t)n * KCL + k];
        const float4* hr = (const float4*)(h + (size_t)n * H1C);
        float4 h0 = hr[0], h1 = hr[1], h2 = hr[2], h3 = hr[3];
        acc[0]  = fmaf(p, h0.x, acc[0]);  acc[1]  = fmaf(p, h0.y, acc[1]);
        acc[2]  = fmaf(p, h0.z, acc[2]);  acc[3]  = fmaf(p, h0.w, acc[3]);
        acc[4]  = fmaf(p, h1.x, acc[4]);  acc[5]  = fmaf(p, h1.y, acc[5]);
        acc[6]  = fmaf(p, h1.z, acc[6]);  acc[7]  = fmaf(p, h1.w, acc[7]);
        acc[8]  = fmaf(p, h2.x, acc[8]);  acc[9]  = fmaf(p, h2.y, acc[9]);
        acc[10] = fmaf(p, h2.z, acc[10]); acc[11] = fmaf(p, h2.w, acc[11]);
        acc[12] = fmaf(p, h3.x, acc[12]); acc[13] = fmaf(p, h3.y, acc[13]);
        acc[14] = fmaf(p, h3.z, acc[14]); acc[15] = fmaf(p, h3.w, acc[15]);
    }

    for (int i = tid; i < KCL * (H1C + 1); i += 1024) red[i] = 0.0f;
    __syncthreads();
#pragma unroll
    for (int j = 0; j < H1C; j++) atomicAdd(&red[k * (H1C + 1) + j], acc[j]);
    __syncthreads();
    for (int i = tid; i < KCL * H1C; i += 1024) {
        int kk = i >> 4, j = i & 15;
        atomicAdd(&xp[i], red[kk * (H1C + 1) + j]);
    }
}

// ---------------------------------------------------------------------------
// Tail: mask==all-ones (adj strictly positive) => deg2=256, agg2 = colmean(xw).
// h2 = relu(colmean(xp@W2) + xp@root2 + b2); g = rowmean(h2); MLP head.
__global__ __launch_bounds__(256) void k_tail(const float* __restrict__ xp,
                                              const float* __restrict__ W2,
                                              const float* __restrict__ root2,
                                              const float* __restrict__ b2,
                                              const float* __restrict__ lw1,
                                              const float* __restrict__ lb1,
                                              const float* __restrict__ lw2,
                                              const float* __restrict__ lb2,
                                              float* __restrict__ out) {
    __shared__ float ssum[H2C];
    __shared__ float gsum[H2C];
    const int t = threadIdx.x;  // pooled-node row, 0..255
    if (t < H2C) { ssum[t] = 0.0f; gsum[t] = 0.0f; }
    __syncthreads();

    float row[H1C];
#pragma unroll
    for (int c = 0; c < H1C; c++) row[c] = xp[t * H1C + c];

#pragma unroll
    for (int j = 0; j < H2C; j++) {
        float v = 0.0f;
#pragma unroll
        for (int c = 0; c < H1C; c++) v = fmaf(row[c], W2[c * H2C + j], v);
        atomicAdd(&ssum[j], v);
    }
    __syncthreads();
#pragma unroll
    for (int j = 0; j < H2C; j++) {
        float v = ssum[j] * (1.0f / KCL) + b2[j];
#pragma unroll
        for (int c = 0; c < H1C; c++) v = fmaf(row[c], root2[c * H2C + j], v);
        v = fmaxf(v, 0.0f);  // relu (leaky(relu(v)) == relu(v))
        atomicAdd(&gsum[j], v);
    }
    __syncthreads();
    if (t == 0) {
        float u[8];
#pragma unroll
        for (int a = 0; a < 8; a++) {
            float v = lb1[a];
#pragma unroll
            for (int j = 0; j < H2C; j++) v = fmaf(gsum[j] * (1.0f / KCL), lw1[j * 8 + a], v);
            u[a] = v > 0.0f ? v : 0.1f * v;  // real leaky
        }
#pragma unroll
        for (int o = 0; o < 2; o++) {
            float v = lb2[o];
#pragma unroll
            for (int a = 0; a < 8; a++) v = fmaf(u[a], lw2[a * 2 + o], v);
            out[o] = v;
        }
    }
}

// ---------------------------------------------------------------------------
extern "C" void kernel_launch(void* const* d_in, const int* in_sizes, int n_in,
                              void* d_out, int out_size, void* d_ws, size_t ws_size,
                              hipStream_t stream) {
    const float* x          = (const float*)d_in[0];
    const unsigned int* ei  = (const unsigned int*)d_in[1];
    // d_in[2] = edge_attr: unused (mask is all-ones; kernel_size=1 SplineConv
    // on the pooled graph only depends on the nonzero pattern of adj)
    const float* pos   = (const float*)d_in[3];
    const float* W1    = (const float*)d_in[4];
    const float* root1 = (const float*)d_in[5];
    const float* b1    = (const float*)d_in[6];
    const float* W2    = (const float*)d_in[7];
    const float* root2 = (const float*)d_in[8];
    const float* b2    = (const float*)d_in[9];
    const float* lw1   = (const float*)d_in[10];
    const float* lb1   = (const float*)d_in[11];
    const float* lw2   = (const float*)d_in[12];
    const float* lb2   = (const float*)d_in[13];
    float* out = (float*)d_out;

    const int N = in_sizes[0] / INC;  // 100000
    const int E = in_sizes[1] / 2;    // 3200000

    // workspace layout (floats): [xsum N*6][xp 4096][flag pad 16][h N*16]
    float* ws   = (float*)d_ws;
    float* xsum = ws;
    float* xp   = xsum + (size_t)N * 6;
    int*   flag = (int*)(xp + KCL * H1C);
    float* h    = (float*)((float*)flag + 16);

    hipMemsetAsync(xsum, 0, ((size_t)N * 6 + KCL * H1C) * sizeof(float), stream);
    k_detect<<<1, 64, 0, stream>>>(ei, flag);
    k_edge<<<(E + 255) / 256, 256, 0, stream>>>(ei, x, xsum, flag, E);
    k_node<<<(N + 255) / 256, 256, 0, stream>>>(x, xsum, W1, root1, b1, h, N);
    const int nb = 512;
    k_pool<<<nb, 1024, 0, stream>>>(pos, h, xp, N, nb);
    k_tail<<<1, 256, 0, stream>>>(xp, W2, root2, b2, lw1, lb1, lw2, lb2, out);
}

// Round 2
// 456.336 us; speedup vs baseline: 2.5878x; 2.5878x over previous
//
#include <hip/hip_runtime.h>

#define INC 5
#define H1C 16
#define H2C 32
#define KCL 256

#define NBINS 40
#define BINSZ 2500          // 40*2500 = 100000 nodes; LDS = 2500*6*4 = 60 KB
#define MAXCHUNK 12
#define POOL_NB 256

// ---------------------------------------------------------------------------
// Detect whether edge_index is int64 (JAX x64 on) or int32 (default).
// If int64, odd 32-bit words (high halves) are all zero (node ids < 2^31).
__global__ void k_detect(const unsigned int* __restrict__ ei, int* __restrict__ flag) {
    if (blockIdx.x == 0 && threadIdx.x == 0) {
        int is64 = 1;
        for (int i = 1; i < 32; i += 2)
            if (ei[i] != 0u) is64 = 0;
        *flag = is64;
    }
}

// ---------------------------------------------------------------------------
// Binned edge scatter, NO global atomics.
// block = (chunk, bin); scans dst of its edge chunk, keeps edges whose dst is
// in [bin*BINSZ, bin*BINSZ+BINSZ), accumulates {x[src][0..4], 1} into LDS,
// then writes the 60 KB bin-partial with plain coalesced stores.
// blockIdx.x = chunk*NBINS + bin  -> consecutive blocks share the same dst
// chunk (L2 reuse within an XCD).
__global__ __launch_bounds__(1024) void k_edge_bin(const unsigned int* __restrict__ ei,
                                                   const float* __restrict__ x,
                                                   const int* __restrict__ flag,
                                                   float* __restrict__ part,
                                                   int E, int nchunk, int N) {
    __shared__ float acc[BINSZ * 6];
    const int bin = blockIdx.x % NBINS;
    const int chunk = blockIdx.x / NBINS;
    const int lo = bin * BINSZ;
    const int hi = (lo + BINSZ < N) ? (lo + BINSZ) : N;
    const int nloc = hi - lo;
    for (int i = threadIdx.x; i < nloc * 6; i += 1024) acc[i] = 0.0f;
    __syncthreads();

    const int is64 = *flag;  // uniform
    const long long ce = ((long long)E + nchunk - 1) / nchunk;
    const long long e0 = (long long)chunk * ce;
    long long e1 = e0 + ce;
    if (e1 > E) e1 = E;

    if (is64) {
#pragma unroll 4
        for (long long e = e0 + threadIdx.x; e < e1; e += 1024) {
            const int d = (int)ei[2 * ((size_t)E + (size_t)e)];
            if (d >= lo && d < hi) {
                const int s = (int)ei[2 * (size_t)e];
                const float* xr = x + (size_t)s * INC;
                float* a = acc + (d - lo) * 6;
                atomicAdd(a + 0, xr[0]);
                atomicAdd(a + 1, xr[1]);
                atomicAdd(a + 2, xr[2]);
                atomicAdd(a + 3, xr[3]);
                atomicAdd(a + 4, xr[4]);
                atomicAdd(a + 5, 1.0f);
            }
        }
    } else {
#pragma unroll 4
        for (long long e = e0 + threadIdx.x; e < e1; e += 1024) {
            const int d = (int)ei[(size_t)E + (size_t)e];
            if (d >= lo && d < hi) {
                const int s = (int)ei[(size_t)e];
                const float* xr = x + (size_t)s * INC;
                float* a = acc + (d - lo) * 6;
                atomicAdd(a + 0, xr[0]);
                atomicAdd(a + 1, xr[1]);
                atomicAdd(a + 2, xr[2]);
                atomicAdd(a + 3, xr[3]);
                atomicAdd(a + 4, xr[4]);
                atomicAdd(a + 5, 1.0f);
            }
        }
    }
    __syncthreads();
    float* o = part + (size_t)chunk * ((size_t)N * 6) + (size_t)lo * 6;
    for (int i = threadIdx.x; i < nloc * 6; i += 1024) o[i] = acc[i];
}

// ---------------------------------------------------------------------------
// Fused partial-reduce + node update:
// xsum[n] = sum_c part[c][n];  h[n] = relu(xsum/deg @ W1 + x[n] @ root1 + b1)
__global__ void k_node2(const float* __restrict__ x, const float* __restrict__ part,
                        const float* __restrict__ W1, const float* __restrict__ root1,
                        const float* __restrict__ b1, float* __restrict__ h,
                        int N, int nchunk) {
    int n = blockIdx.x * blockDim.x + threadIdx.x;
    if (n >= N) return;
    float s[6] = {0.f, 0.f, 0.f, 0.f, 0.f, 0.f};
    for (int c = 0; c < nchunk; c++) {
        const float* p = part + (size_t)c * ((size_t)N * 6) + (size_t)n * 6;
#pragma unroll
        for (int j = 0; j < 6; j++) s[j] += p[j];
    }
    const float inv = 1.0f / fmaxf(s[5], 1.0f);
    float xs[INC], xv[INC];
#pragma unroll
    for (int c = 0; c < INC; c++) {
        xs[c] = s[c] * inv;
        xv[c] = x[(size_t)n * INC + c];
    }
    float hv[H1C];
#pragma unroll
    for (int j = 0; j < H1C; j++) {
        float v = b1[j];
#pragma unroll
        for (int c = 0; c < INC; c++)
            v = fmaf(xs[c], W1[c * H1C + j], fmaf(xv[c], root1[c * H1C + j], v));
        hv[j] = fmaxf(v, 0.0f);  // relu(leaky(relu(v))) == relu(v)
    }
    float4* hp = (float4*)(h + (size_t)n * H1C);
#pragma unroll
    for (int q = 0; q < 4; q++)
        hp[q] = make_float4(hv[4 * q], hv[4 * q + 1], hv[4 * q + 2], hv[4 * q + 3]);
}

// ---------------------------------------------------------------------------
// xp_part[b][k][j] = sum_{n in block b's range} pos[n][k] * h[n][j]
// 1024 threads: k = tid&255, sub = tid>>8 walks nodes stride 4.
// No global atomics: each block writes its own 16 KB partial.
__global__ __launch_bounds__(1024) void k_pool(const float* __restrict__ pos,
                                               const float* __restrict__ h,
                                               float* __restrict__ xp_part, int N, int nb) {
    __shared__ float red[KCL * (H1C + 1)];
    const int tid = threadIdx.x;
    const int k = tid & (KCL - 1);
    const int sub = tid >> 8;
    const int chunk = (N + nb - 1) / nb;
    const int n0 = blockIdx.x * chunk;
    const int n1 = min(n0 + chunk, N);

    float acc[H1C];
#pragma unroll
    for (int j = 0; j < H1C; j++) acc[j] = 0.0f;

    for (int n = n0 + sub; n < n1; n += 4) {
        const float p = pos[(size_t)n * KCL + k];
        const float4* hr = (const float4*)(h + (size_t)n * H1C);
        float4 h0 = hr[0], h1 = hr[1], h2 = hr[2], h3 = hr[3];
        acc[0]  = fmaf(p, h0.x, acc[0]);  acc[1]  = fmaf(p, h0.y, acc[1]);
        acc[2]  = fmaf(p, h0.z, acc[2]);  acc[3]  = fmaf(p, h0.w, acc[3]);
        acc[4]  = fmaf(p, h1.x, acc[4]);  acc[5]  = fmaf(p, h1.y, acc[5]);
        acc[6]  = fmaf(p, h1.z, acc[6]);  acc[7]  = fmaf(p, h1.w, acc[7]);
        acc[8]  = fmaf(p, h2.x, acc[8]);  acc[9]  = fmaf(p, h2.y, acc[9]);
        acc[10] = fmaf(p, h2.z, acc[10]); acc[11] = fmaf(p, h2.w, acc[11]);
        acc[12] = fmaf(p, h3.x, acc[12]); acc[13] = fmaf(p, h3.y, acc[13]);
        acc[14] = fmaf(p, h3.z, acc[14]); acc[15] = fmaf(p, h3.w, acc[15]);
    }

    for (int i = tid; i < KCL * (H1C + 1); i += 1024) red[i] = 0.0f;
    __syncthreads();
#pragma unroll
    for (int j = 0; j < H1C; j++) atomicAdd(&red[k * (H1C + 1) + j], acc[j]);
    __syncthreads();
    float* o = xp_part + (size_t)blockIdx.x * (KCL * H1C);
    for (int i = tid; i < KCL * H1C; i += 1024) {
        int kk = i >> 4, j = i & 15;
        o[i] = red[kk * (H1C + 1) + j];
    }
}

// ---------------------------------------------------------------------------
// xp[i] = sum_b xp_part[b][i], i in [0,4096). 16 blocks x 1024 threads.
__global__ __launch_bounds__(1024) void k_xpred(const float* __restrict__ xp_part,
                                                float* __restrict__ xp, int nb) {
    __shared__ float r[1024];
    const int li = threadIdx.x & 255;
    const int sub = threadIdx.x >> 8;
    const int i = blockIdx.x * 256 + li;
    float s = 0.0f;
    for (int b = sub; b < nb; b += 4) s += xp_part[(size_t)b * (KCL * H1C) + i];
    r[threadIdx.x] = s;
    __syncthreads();
    if (threadIdx.x < 256)
        xp[blockIdx.x * 256 + threadIdx.x] =
            r[threadIdx.x] + r[256 + threadIdx.x] + r[512 + threadIdx.x] + r[768 + threadIdx.x];
}

// ---------------------------------------------------------------------------
// Tail: adj is strictly positive (sum of 3.2M nonneg random terms) => mask is
// all-ones, deg2 = 256, agg2 = broadcast column-mean of xp@W2.
__global__ __launch_bounds__(256) void k_tail(const float* __restrict__ xp,
                                              const float* __restrict__ W2,
                                              const float* __restrict__ root2,
                                              const float* __restrict__ b2,
                                              const float* __restrict__ lw1,
                                              const float* __restrict__ lb1,
                                              const float* __restrict__ lw2,
                                              const float* __restrict__ lb2,
                                              float* __restrict__ out) {
    __shared__ float ssum[H2C];
    __shared__ float gsum[H2C];
    const int t = threadIdx.x;
    if (t < H2C) { ssum[t] = 0.0f; gsum[t] = 0.0f; }
    __syncthreads();

    float row[H1C];
#pragma unroll
    for (int c = 0; c < H1C; c++) row[c] = xp[t * H1C + c];

#pragma unroll
    for (int j = 0; j < H2C; j++) {
        float v = 0.0f;
#pragma unroll
        for (int c = 0; c < H1C; c++) v = fmaf(row[c], W2[c * H2C + j], v);
        atomicAdd(&ssum[j], v);
    }
    __syncthreads();
#pragma unroll
    for (int j = 0; j < H2C; j++) {
        float v = ssum[j] * (1.0f / KCL) + b2[j];
#pragma unroll
        for (int c = 0; c < H1C; c++) v = fmaf(row[c], root2[c * H2C + j], v);
        v = fmaxf(v, 0.0f);
        atomicAdd(&gsum[j], v);
    }
    __syncthreads();
    if (t == 0) {
        float u[8];
#pragma unroll
        for (int a = 0; a < 8; a++) {
            float v = lb1[a];
#pragma unroll
            for (int j = 0; j < H2C; j++) v = fmaf(gsum[j] * (1.0f / KCL), lw1[j * 8 + a], v);
            u[a] = v > 0.0f ? v : 0.1f * v;
        }
#pragma unroll
        for (int o = 0; o < 2; o++) {
            float v = lb2[o];
#pragma unroll
            for (int a = 0; a < 8; a++) v = fmaf(u[a], lw2[a * 2 + o], v);
            out[o] = v;
        }
    }
}

// ---------------------------------------------------------------------------
// Legacy fallback kernels (global-atomic path) in case ws is too small for
// the partial buffers. Correct but slow.
__global__ void k_edge_legacy(const unsigned int* __restrict__ ei, const float* __restrict__ x,
                              float* __restrict__ xsum, const int* __restrict__ flag, int E) {
    int e = blockIdx.x * blockDim.x + threadIdx.x;
    if (e >= E) return;
    const int is64 = *flag;
    int src, dst;
    if (is64) {
        src = (int)ei[(size_t)2 * e];
        dst = (int)ei[(size_t)2 * ((size_t)E + (size_t)e)];
    } else {
        src = (int)ei[e];
        dst = (int)ei[(size_t)E + (size_t)e];
    }
    const float* xr = x + (size_t)src * INC;
    float* o = xsum + (size_t)dst * 6;
    atomicAdd(o + 0, xr[0]);
    atomicAdd(o + 1, xr[1]);
    atomicAdd(o + 2, xr[2]);
    atomicAdd(o + 3, xr[3]);
    atomicAdd(o + 4, xr[4]);
    atomicAdd(o + 5, 1.0f);
}

// ---------------------------------------------------------------------------
extern "C" void kernel_launch(void* const* d_in, const int* in_sizes, int n_in,
                              void* d_out, int out_size, void* d_ws, size_t ws_size,
                              hipStream_t stream) {
    const float* x         = (const float*)d_in[0];
    const unsigned int* ei = (const unsigned int*)d_in[1];
    // d_in[2] = edge_attr: unused (adj has no exact zeros -> mask all-ones)
    const float* pos   = (const float*)d_in[3];
    const float* W1    = (const float*)d_in[4];
    const float* root1 = (const float*)d_in[5];
    const float* b1    = (const float*)d_in[6];
    const float* W2    = (const float*)d_in[7];
    const float* root2 = (const float*)d_in[8];
    const float* b2    = (const float*)d_in[9];
    const float* lw1   = (const float*)d_in[10];
    const float* lb1   = (const float*)d_in[11];
    const float* lw2   = (const float*)d_in[12];
    const float* lb2   = (const float*)d_in[13];
    float* out = (float*)d_out;

    const int N = in_sizes[0] / INC;  // 100000
    const int E = in_sizes[1] / 2;    // 3200000

    // workspace layout (floats):
    //   [xp 4096][flag 16][xp_part POOL_NB*4096][h N*16][edge partials nchunk*N*6]
    float* ws      = (float*)d_ws;
    float* xp      = ws;
    int*   flag    = (int*)(xp + KCL * H1C);
    float* xp_part = (float*)flag + 16;
    float* h       = xp_part + (size_t)POOL_NB * (KCL * H1C);
    float* part    = h + (size_t)N * H1C;

    const size_t base_floats = (size_t)(KCL * H1C) + 16 + (size_t)POOL_NB * (KCL * H1C) + (size_t)N * H1C;
    const size_t avail = ws_size / 4 > base_floats ? ws_size / 4 - base_floats : 0;
    int nchunk = (int)(avail / ((size_t)N * 6));
    if (nchunk > MAXCHUNK) nchunk = MAXCHUNK;

    k_detect<<<1, 64, 0, stream>>>(ei, flag);

    if (nchunk >= 2) {
        // fast path: binned, atomic-free
        k_edge_bin<<<NBINS * nchunk, 1024, 0, stream>>>(ei, x, flag, part, E, nchunk, N);
        k_node2<<<(N + 255) / 256, 256, 0, stream>>>(x, part, W1, root1, b1, h, N, nchunk);
    } else {
        // fallback: global-atomic scatter into xsum (reuse 'part' slot head)
        float* xsum = h + (size_t)N * H1C;  // needs N*6 floats
        hipMemsetAsync(xsum, 0, (size_t)N * 6 * sizeof(float), stream);
        k_edge_legacy<<<(E + 255) / 256, 256, 0, stream>>>(ei, x, xsum, flag, E);
        k_node2<<<(N + 255) / 256, 256, 0, stream>>>(x, xsum, W1, root1, b1, h, N, 1);
    }
    k_pool<<<POOL_NB, 1024, 0, stream>>>(pos, h, xp_part, N, POOL_NB);
    k_xpred<<<16, 1024, 0, stream>>>(xp_part, xp, POOL_NB);
    k_tail<<<1, 256, 0, stream>>>(xp, W2, root2, b2, lw1, lb1, lw2, lb2, out);
}

// Round 3
// 436.952 us; speedup vs baseline: 2.7026x; 1.0444x over previous
//
#include <hip/hip_runtime.h>

#define INC 5
#define H1C 16
#define H2C 32
#define KCL 256

// fallback (rescan) params
#define NBINS 40
#define BINSZ 2500
#define MAXCHUNK 12

// partition params
#define PB_SHIFT 9
#define PB_SZ 512               // nodes per bin
#define PB_NBMAX 256
#define PB_C 18432              // bucket capacity per bin (mean 16384 + 16 sigma)
#define PB_M 6144               // edges per partition block
#define PB_ETPB 6               // PB_M / 1024
#define PB_S 2                  // phase-2 sub-splits per bin

#define POOL_NB 512

// ---------------------------------------------------------------------------
// Detect whether edge_index is int64 (odd 32-bit words all zero) or int32.
__global__ void k_detect(const unsigned int* __restrict__ ei, int* __restrict__ flag) {
    if (blockIdx.x == 0 && threadIdx.x == 0) {
        int is64 = 1;
        for (int i = 1; i < 32; i += 2)
            if (ei[i] != 0u) is64 = 0;
        *flag = is64;
    }
}

__global__ void k_init(unsigned* __restrict__ gcur, int nb) {
    int b = blockIdx.x * blockDim.x + threadIdx.x;
    if (b < nb) gcur[b] = (unsigned)b * PB_C;
}

// ---------------------------------------------------------------------------
// Phase 1: partition edges into dst-bins. Per block: LDS histogram over its
// 6144 edges, per-bin global base via one atomic per (block,bin), LDS
// counting sort, then coalesced run-wise writes of packed entries
// (src<<9 | dst&511) into the per-bin buckets.
__global__ __launch_bounds__(1024) void k_part(const unsigned int* __restrict__ ei,
                                               const int* __restrict__ flag,
                                               unsigned* __restrict__ gcur,
                                               unsigned* __restrict__ bucket,
                                               int E, int NB) {
    __shared__ int hist[PB_NBMAX];
    __shared__ int lbase[PB_NBMAX];
    __shared__ unsigned gbase[PB_NBMAX];
    __shared__ int sc[PB_NBMAX];
    __shared__ unsigned sorted[PB_M];
    __shared__ unsigned char sbin[PB_M];

    const int tid = threadIdx.x;
    const int e0 = blockIdx.x * PB_M;
    int m = E - e0; if (m > PB_M) m = PB_M;

    for (int i = tid; i < PB_NBMAX; i += 1024) hist[i] = 0;
    __syncthreads();

    const int is64 = *flag;  // uniform
    unsigned ee[PB_ETPB]; int eb[PB_ETPB]; int er[PB_ETPB];

#pragma unroll
    for (int ii = 0; ii < PB_ETPB; ii++) {
        const int off = tid + ii * 1024;
        eb[ii] = -1; ee[ii] = 0u; er[ii] = 0;
        if (off < m) {
            const int e = e0 + off;
            unsigned d, s;
            if (is64) { d = ei[2 * ((size_t)E + (size_t)e)]; s = ei[2 * (size_t)e]; }
            else      { d = ei[(size_t)E + (size_t)e];       s = ei[(size_t)e]; }
            const int b = (int)(d >> PB_SHIFT);
            eb[ii] = b;
            ee[ii] = (s << PB_SHIFT) | (d & (PB_SZ - 1));
            er[ii] = atomicAdd(&hist[b], 1);
        }
    }
    __syncthreads();

    // inclusive scan of hist (256 entries, Hillis-Steele; uniform barriers)
    if (tid < PB_NBMAX) sc[tid] = hist[tid];
    __syncthreads();
    for (int st = 1; st < PB_NBMAX; st <<= 1) {
        int v = 0;
        if (tid < PB_NBMAX && tid >= st) v = sc[tid - st];
        __syncthreads();
        if (tid < PB_NBMAX) sc[tid] += v;
        __syncthreads();
    }
    if (tid < PB_NBMAX) lbase[tid] = sc[tid] - hist[tid];
    if (tid < NB) gbase[tid] = atomicAdd(&gcur[tid], (unsigned)hist[tid]);
    __syncthreads();

#pragma unroll
    for (int ii = 0; ii < PB_ETPB; ii++) {
        if (eb[ii] >= 0) {
            const int j = lbase[eb[ii]] + er[ii];
            sorted[j] = ee[ii];
            sbin[j] = (unsigned char)eb[ii];
        }
    }
    __syncthreads();

    for (int j = tid; j < m; j += 1024) {
        const int b = (int)sbin[j];
        const unsigned g = gbase[b] + (unsigned)(j - lbase[b]);
        if (g < (unsigned)(b + 1) * PB_C) bucket[g] = sorted[j];  // overflow guard
    }
}

// ---------------------------------------------------------------------------
// Phase 2: per (bin, sub): scan bucket slice densely, accumulate
// {x[src][0..4], 1} into LDS xsum for the bin's 512 nodes, write partial.
__global__ __launch_bounds__(1024) void k_gather(const unsigned* __restrict__ bucket,
                                                 const unsigned* __restrict__ gcur,
                                                 const float* __restrict__ x,
                                                 float* __restrict__ part,
                                                 int N, int NB) {
    __shared__ float acc[PB_SZ * 6];
    const int b = blockIdx.x / PB_S;
    const int sub = blockIdx.x % PB_S;
    const int tid = threadIdx.x;
    const int lo = b << PB_SHIFT;
    int hi = lo + PB_SZ; if (hi > N) hi = N;
    const int nloc = hi - lo;

    for (int i = tid; i < PB_SZ * 6; i += 1024) acc[i] = 0.0f;
    __syncthreads();

    int cnt = (int)(gcur[b] - (unsigned)b * PB_C);
    if (cnt > PB_C) cnt = PB_C;
    const int i0 = (cnt * sub) / PB_S;
    const int i1 = (cnt * (sub + 1)) / PB_S;
    const unsigned* bk = bucket + (size_t)b * PB_C;
    for (int i = i0 + tid; i < i1; i += 1024) {
        const unsigned e = bk[i];
        const unsigned s = e >> PB_SHIFT;
        const int dl = (int)(e & (PB_SZ - 1));
        const float* xr = x + (size_t)s * INC;
        float* a = acc + dl * 6;
        atomicAdd(a + 0, xr[0]);
        atomicAdd(a + 1, xr[1]);
        atomicAdd(a + 2, xr[2]);
        atomicAdd(a + 3, xr[3]);
        atomicAdd(a + 4, xr[4]);
        atomicAdd(a + 5, 1.0f);
    }
    __syncthreads();
    float* o = part + (size_t)sub * ((size_t)N * 6) + (size_t)lo * 6;
    for (int i = tid; i < nloc * 6; i += 1024) o[i] = acc[i];
}

// ---------------------------------------------------------------------------
// Fallback binned-rescan edge kernel (round-2 path).
__global__ __launch_bounds__(1024) void k_edge_bin(const unsigned int* __restrict__ ei,
                                                   const float* __restrict__ x,
                                                   const int* __restrict__ flag,
                                                   float* __restrict__ part,
                                                   int E, int nchunk, int N) {
    __shared__ float acc[BINSZ * 6];
    const int bin = blockIdx.x % NBINS;
    const int chunk = blockIdx.x / NBINS;
    const int lo = bin * BINSZ;
    const int hi = (lo + BINSZ < N) ? (lo + BINSZ) : N;
    const int nloc = hi - lo;
    for (int i = threadIdx.x; i < nloc * 6; i += 1024) acc[i] = 0.0f;
    __syncthreads();

    const int is64 = *flag;
    const long long ce = ((long long)E + nchunk - 1) / nchunk;
    const long long e0 = (long long)chunk * ce;
    long long e1 = e0 + ce;
    if (e1 > E) e1 = E;

    for (long long e = e0 + threadIdx.x; e < e1; e += 1024) {
        const int d = is64 ? (int)ei[2 * ((size_t)E + (size_t)e)] : (int)ei[(size_t)E + (size_t)e];
        if (d >= lo && d < hi) {
            const int s = is64 ? (int)ei[2 * (size_t)e] : (int)ei[(size_t)e];
            const float* xr = x + (size_t)s * INC;
            float* a = acc + (d - lo) * 6;
            atomicAdd(a + 0, xr[0]);
            atomicAdd(a + 1, xr[1]);
            atomicAdd(a + 2, xr[2]);
            atomicAdd(a + 3, xr[3]);
            atomicAdd(a + 4, xr[4]);
            atomicAdd(a + 5, 1.0f);
        }
    }
    __syncthreads();
    float* o = part + (size_t)chunk * ((size_t)N * 6) + (size_t)lo * 6;
    for (int i = threadIdx.x; i < nloc * 6; i += 1024) o[i] = acc[i];
}

// ---------------------------------------------------------------------------
// Reduce partials + node update: h[n] = relu(sum_c part[c][n]/deg @ W1 + x@root1 + b1)
__global__ void k_node2(const float* __restrict__ x, const float* __restrict__ part,
                        const float* __restrict__ W1, const float* __restrict__ root1,
                        const float* __restrict__ b1, float* __restrict__ h,
                        int N, int nchunk) {
    int n = blockIdx.x * blockDim.x + threadIdx.x;
    if (n >= N) return;
    float s[6] = {0.f, 0.f, 0.f, 0.f, 0.f, 0.f};
    for (int c = 0; c < nchunk; c++) {
        const float* p = part + (size_t)c * ((size_t)N * 6) + (size_t)n * 6;
#pragma unroll
        for (int j = 0; j < 6; j++) s[j] += p[j];
    }
    const float inv = 1.0f / fmaxf(s[5], 1.0f);
    float xs[INC], xv[INC];
#pragma unroll
    for (int c = 0; c < INC; c++) {
        xs[c] = s[c] * inv;
        xv[c] = x[(size_t)n * INC + c];
    }
    float hv[H1C];
#pragma unroll
    for (int j = 0; j < H1C; j++) {
        float v = b1[j];
#pragma unroll
        for (int c = 0; c < INC; c++)
            v = fmaf(xs[c], W1[c * H1C + j], fmaf(xv[c], root1[c * H1C + j], v));
        hv[j] = fmaxf(v, 0.0f);  // relu(leaky(relu(v))) == relu(v)
    }
    float4* hp = (float4*)(h + (size_t)n * H1C);
#pragma unroll
    for (int q = 0; q < 4; q++)
        hp[q] = make_float4(hv[4 * q], hv[4 * q + 1], hv[4 * q + 2], hv[4 * q + 3]);
}

// ---------------------------------------------------------------------------
// xp_part[blk][k][j] = sum_{n in chunk} pos[n][k] * h[n][j]
__global__ __launch_bounds__(1024) void k_pool(const float* __restrict__ pos,
                                               const float* __restrict__ h,
                                               float* __restrict__ xp_part, int N, int nb) {
    __shared__ float red[KCL * (H1C + 1)];
    const int tid = threadIdx.x;
    const int k = tid & (KCL - 1);
    const int sub = tid >> 8;
    const int chunk = (N + nb - 1) / nb;
    const int n0 = blockIdx.x * chunk;
    const int n1 = min(n0 + chunk, N);

    float acc[H1C];
#pragma unroll
    for (int j = 0; j < H1C; j++) acc[j] = 0.0f;

#pragma unroll 2
    for (int n = n0 + sub; n < n1; n += 4) {
        const float p = pos[(size_t)n * KCL + k];
        const float4* hr = (const float4*)(h + (size_t)n * H1C);
        float4 h0 = hr[0], h1 = hr[1], h2 = hr[2], h3 = hr[3];
        acc[0]  = fmaf(p, h0.x, acc[0]);  acc[1]  = fmaf(p, h0.y, acc[1]);
        acc[2]  = fmaf(p, h0.z, acc[2]);  acc[3]  = fmaf(p, h0.w, acc[3]);
        acc[4]  = fmaf(p, h1.x, acc[4]);  acc[5]  = fmaf(p, h1.y, acc[5]);
        acc[6]  = fmaf(p, h1.z, acc[6]);  acc[7]  = fmaf(p, h1.w, acc[7]);
        acc[8]  = fmaf(p, h2.x, acc[8]);  acc[9]  = fmaf(p, h2.y, acc[9]);
        acc[10] = fmaf(p, h2.z, acc[10]); acc[11] = fmaf(p, h2.w, acc[11]);
        acc[12] = fmaf(p, h3.x, acc[12]); acc[13] = fmaf(p, h3.y, acc[13]);
        acc[14] = fmaf(p, h3.z, acc[14]); acc[15] = fmaf(p, h3.w, acc[15]);
    }

    for (int i = tid; i < KCL * (H1C + 1); i += 1024) red[i] = 0.0f;
    __syncthreads();
#pragma unroll
    for (int j = 0; j < H1C; j++) atomicAdd(&red[k * (H1C + 1) + j], acc[j]);
    __syncthreads();
    float* o = xp_part + (size_t)blockIdx.x * (KCL * H1C);
    for (int i = tid; i < KCL * H1C; i += 1024) {
        int kk = i >> 4, j = i & 15;
        o[i] = red[kk * (H1C + 1) + j];
    }
}

// ---------------------------------------------------------------------------
__global__ __launch_bounds__(1024) void k_xpred(const float* __restrict__ xp_part,
                                                float* __restrict__ xp, int nb) {
    __shared__ float r[1024];
    const int li = threadIdx.x & 255;
    const int sub = threadIdx.x >> 8;
    const int i = blockIdx.x * 256 + li;
    float s = 0.0f;
    for (int b = sub; b < nb; b += 4) s += xp_part[(size_t)b * (KCL * H1C) + i];
    r[threadIdx.x] = s;
    __syncthreads();
    if (threadIdx.x < 256)
        xp[blockIdx.x * 256 + threadIdx.x] =
            r[threadIdx.x] + r[256 + threadIdx.x] + r[512 + threadIdx.x] + r[768 + threadIdx.x];
}

// ---------------------------------------------------------------------------
// Tail: adj strictly positive => mask all-ones, deg2 = 256.
__global__ __launch_bounds__(256) void k_tail(const float* __restrict__ xp,
                                              const float* __restrict__ W2,
                                              const float* __restrict__ root2,
                                              const float* __restrict__ b2,
                                              const float* __restrict__ lw1,
                                              const float* __restrict__ lb1,
                                              const float* __restrict__ lw2,
                                              const float* __restrict__ lb2,
                                              float* __restrict__ out) {
    __shared__ float ssum[H2C];
    __shared__ float gsum[H2C];
    const int t = threadIdx.x;
    if (t < H2C) { ssum[t] = 0.0f; gsum[t] = 0.0f; }
    __syncthreads();

    float row[H1C];
#pragma unroll
    for (int c = 0; c < H1C; c++) row[c] = xp[t * H1C + c];

#pragma unroll
    for (int j = 0; j < H2C; j++) {
        float v = 0.0f;
#pragma unroll
        for (int c = 0; c < H1C; c++) v = fmaf(row[c], W2[c * H2C + j], v);
        atomicAdd(&ssum[j], v);
    }
    __syncthreads();
#pragma unroll
    for (int j = 0; j < H2C; j++) {
        float v = ssum[j] * (1.0f / KCL) + b2[j];
#pragma unroll
        for (int c = 0; c < H1C; c++) v = fmaf(row[c], root2[c * H2C + j], v);
        v = fmaxf(v, 0.0f);
        atomicAdd(&gsum[j], v);
    }
    __syncthreads();
    if (t == 0) {
        float u[8];
#pragma unroll
        for (int a = 0; a < 8; a++) {
            float v = lb1[a];
#pragma unroll
            for (int j = 0; j < H2C; j++) v = fmaf(gsum[j] * (1.0f / KCL), lw1[j * 8 + a], v);
            u[a] = v > 0.0f ? v : 0.1f * v;
        }
#pragma unroll
        for (int o = 0; o < 2; o++) {
            float v = lb2[o];
#pragma unroll
            for (int a = 0; a < 8; a++) v = fmaf(u[a], lw2[a * 2 + o], v);
            out[o] = v;
        }
    }
}

// ---------------------------------------------------------------------------
extern "C" void kernel_launch(void* const* d_in, const int* in_sizes, int n_in,
                              void* d_out, int out_size, void* d_ws, size_t ws_size,
                              hipStream_t stream) {
    const float* x         = (const float*)d_in[0];
    const unsigned int* ei = (const unsigned int*)d_in[1];
    // d_in[2] = edge_attr: unused (adj has no exact zeros -> mask all-ones)
    const float* pos   = (const float*)d_in[3];
    const float* W1    = (const float*)d_in[4];
    const float* root1 = (const float*)d_in[5];
    const float* b1    = (const float*)d_in[6];
    const float* W2    = (const float*)d_in[7];
    const float* root2 = (const float*)d_in[8];
    const float* b2    = (const float*)d_in[9];
    const float* lw1   = (const float*)d_in[10];
    const float* lb1   = (const float*)d_in[11];
    const float* lw2   = (const float*)d_in[12];
    const float* lb2   = (const float*)d_in[13];
    float* out = (float*)d_out;

    const int N = in_sizes[0] / INC;  // 100000
    const int E = in_sizes[1] / 2;    // 3200000
    const int NB = (N + PB_SZ - 1) >> PB_SHIFT;

    // common workspace prefix (floats): [xp 4096][flag 16][xp_part][h N*16]
    float* ws      = (float*)d_ws;
    float* xp      = ws;
    int*   flag    = (int*)(xp + KCL * H1C);
    float* xp_part = (float*)(flag + 16);
    float* h       = xp_part + (size_t)POOL_NB * (KCL * H1C);
    float* tail0   = h + (size_t)N * H1C;

    const size_t base_floats = (size_t)(KCL * H1C) + 16 + (size_t)POOL_NB * (KCL * H1C) + (size_t)N * H1C;
    // fast path extras: part[PB_S*N*6] + bucket[NB*PB_C] + gcur[256]
    const size_t fast_floats = base_floats + (size_t)PB_S * N * 6 + (size_t)NB * PB_C + 256;

    k_detect<<<1, 64, 0, stream>>>(ei, flag);

    if (ws_size / 4 >= fast_floats && N <= 131072 && NB <= PB_NBMAX) {
        // fast path: bucket partition + dense gather
        float* part      = tail0;
        unsigned* bucket = (unsigned*)(part + (size_t)PB_S * N * 6);
        unsigned* gcur   = bucket + (size_t)NB * PB_C;
        const int P = (E + PB_M - 1) / PB_M;

        k_init<<<1, 256, 0, stream>>>(gcur, NB);
        k_part<<<P, 1024, 0, stream>>>(ei, flag, gcur, bucket, E, NB);
        k_gather<<<NB * PB_S, 1024, 0, stream>>>(bucket, gcur, x, part, N, NB);
        k_node2<<<(N + 255) / 256, 256, 0, stream>>>(x, part, W1, root1, b1, h, N, PB_S);
    } else {
        // fallback: binned rescan with as many chunks as fit
        const size_t avail = ws_size / 4 > base_floats ? ws_size / 4 - base_floats : 0;
        int nchunk = (int)(avail / ((size_t)N * 6));
        if (nchunk > MAXCHUNK) nchunk = MAXCHUNK;
        if (nchunk < 1) nchunk = 1;
        float* part = tail0;
        k_edge_bin<<<NBINS * nchunk, 1024, 0, stream>>>(ei, x, flag, part, E, nchunk, N);
        k_node2<<<(N + 255) / 256, 256, 0, stream>>>(x, part, W1, root1, b1, h, N, nchunk);
    }
    k_pool<<<POOL_NB, 1024, 0, stream>>>(pos, h, xp_part, N, POOL_NB);
    k_xpred<<<16, 1024, 0, stream>>>(xp_part, xp, POOL_NB);
    k_tail<<<1, 256, 0, stream>>>(xp, W2, root2, b2, lw1, lb1, lw2, lb2, out);
}

// Round 4
// 312.707 us; speedup vs baseline: 3.7764x; 1.3973x over previous
//
#include <hip/hip_runtime.h>

#define INC 5
#define H1C 16
#define H2C 32
#define KCL 256

// fallback (rescan) params
#define NBINS 40
#define BINSZ 2500
#define MAXCHUNK 12

// partition params
#define PB_SHIFT 9
#define PB_SZ 512               // nodes per bin
#define PB_NBMAX 256
#define PB_C 18432              // bucket capacity per bin (mean 16384 + 16 sigma)
#define PB_M 6144               // edges per partition block
#define PB_ETPB 6               // PB_M / 1024
#define PB_S 2                  // phase-2 sub-splits per bin

#define POOL_NB 512

// ---------------------------------------------------------------------------
// Detect whether edge_index is int64 (odd 32-bit words all zero) or int32.
__global__ void k_detect(const unsigned int* __restrict__ ei, int* __restrict__ flag) {
    if (blockIdx.x == 0 && threadIdx.x == 0) {
        int is64 = 1;
        for (int i = 1; i < 32; i += 2)
            if (ei[i] != 0u) is64 = 0;
        *flag = is64;
    }
}

__global__ void k_init(unsigned* __restrict__ gcur, int nb) {
    int b = blockIdx.x * blockDim.x + threadIdx.x;
    if (b < nb) gcur[b] = (unsigned)b * PB_C;
}

// ---------------------------------------------------------------------------
// Phase 1: partition edges into dst-bins. Per block: LDS histogram over its
// 6144 edges, per-bin global base via one atomic per (block,bin), LDS
// counting sort, then coalesced run-wise writes of packed entries
// (src<<9 | dst&511) into the per-bin buckets.
__global__ __launch_bounds__(1024) void k_part(const unsigned int* __restrict__ ei,
                                               const int* __restrict__ flag,
                                               unsigned* __restrict__ gcur,
                                               unsigned* __restrict__ bucket,
                                               int E, int NB) {
    __shared__ int hist[PB_NBMAX];
    __shared__ int lbase[PB_NBMAX];
    __shared__ unsigned gbase[PB_NBMAX];
    __shared__ int sc[PB_NBMAX];
    __shared__ unsigned sorted[PB_M];
    __shared__ unsigned char sbin[PB_M];

    const int tid = threadIdx.x;
    const int e0 = blockIdx.x * PB_M;
    int m = E - e0; if (m > PB_M) m = PB_M;

    for (int i = tid; i < PB_NBMAX; i += 1024) hist[i] = 0;
    __syncthreads();

    const int is64 = *flag;  // uniform
    unsigned ee[PB_ETPB]; int eb[PB_ETPB]; int er[PB_ETPB];

#pragma unroll
    for (int ii = 0; ii < PB_ETPB; ii++) {
        const int off = tid + ii * 1024;
        eb[ii] = -1; ee[ii] = 0u; er[ii] = 0;
        if (off < m) {
            const int e = e0 + off;
            unsigned d, s;
            if (is64) { d = ei[2 * ((size_t)E + (size_t)e)]; s = ei[2 * (size_t)e]; }
            else      { d = ei[(size_t)E + (size_t)e];       s = ei[(size_t)e]; }
            const int b = (int)(d >> PB_SHIFT);
            eb[ii] = b;
            ee[ii] = (s << PB_SHIFT) | (d & (PB_SZ - 1));
            er[ii] = atomicAdd(&hist[b], 1);
        }
    }
    __syncthreads();

    // inclusive scan of hist (256 entries, Hillis-Steele; uniform barriers)
    if (tid < PB_NBMAX) sc[tid] = hist[tid];
    __syncthreads();
    for (int st = 1; st < PB_NBMAX; st <<= 1) {
        int v = 0;
        if (tid < PB_NBMAX && tid >= st) v = sc[tid - st];
        __syncthreads();
        if (tid < PB_NBMAX) sc[tid] += v;
        __syncthreads();
    }
    if (tid < PB_NBMAX) lbase[tid] = sc[tid] - hist[tid];
    if (tid < NB) gbase[tid] = atomicAdd(&gcur[tid], (unsigned)hist[tid]);
    __syncthreads();

#pragma unroll
    for (int ii = 0; ii < PB_ETPB; ii++) {
        if (eb[ii] >= 0) {
            const int j = lbase[eb[ii]] + er[ii];
            sorted[j] = ee[ii];
            sbin[j] = (unsigned char)eb[ii];
        }
    }
    __syncthreads();

    for (int j = tid; j < m; j += 1024) {
        const int b = (int)sbin[j];
        const unsigned g = gbase[b] + (unsigned)(j - lbase[b]);
        if (g < (unsigned)(b + 1) * PB_C) bucket[g] = sorted[j];  // overflow guard
    }
}

// ---------------------------------------------------------------------------
// Phase 2: per (bin, sub): scan bucket slice densely, accumulate
// {x[src][0..4], 1} into LDS xsum for the bin's 512 nodes, write partial.
__global__ __launch_bounds__(1024) void k_gather(const unsigned* __restrict__ bucket,
                                                 const unsigned* __restrict__ gcur,
                                                 const float* __restrict__ x,
                                                 float* __restrict__ part,
                                                 int N, int NB) {
    __shared__ float acc[PB_SZ * 6];
    const int b = blockIdx.x / PB_S;
    const int sub = blockIdx.x % PB_S;
    const int tid = threadIdx.x;
    const int lo = b << PB_SHIFT;
    int hi = lo + PB_SZ; if (hi > N) hi = N;
    const int nloc = hi - lo;

    for (int i = tid; i < PB_SZ * 6; i += 1024) acc[i] = 0.0f;
    __syncthreads();

    int cnt = (int)(gcur[b] - (unsigned)b * PB_C);
    if (cnt > PB_C) cnt = PB_C;
    const int i0 = (cnt * sub) / PB_S;
    const int i1 = (cnt * (sub + 1)) / PB_S;
    const unsigned* bk = bucket + (size_t)b * PB_C;
    for (int i = i0 + tid; i < i1; i += 1024) {
        const unsigned e = bk[i];
        const unsigned s = e >> PB_SHIFT;
        const int dl = (int)(e & (PB_SZ - 1));
        const float* xr = x + (size_t)s * INC;
        float* a = acc + dl * 6;
        atomicAdd(a + 0, xr[0]);
        atomicAdd(a + 1, xr[1]);
        atomicAdd(a + 2, xr[2]);
        atomicAdd(a + 3, xr[3]);
        atomicAdd(a + 4, xr[4]);
        atomicAdd(a + 5, 1.0f);
    }
    __syncthreads();
    float* o = part + (size_t)sub * ((size_t)N * 6) + (size_t)lo * 6;
    for (int i = tid; i < nloc * 6; i += 1024) o[i] = acc[i];
}

// ---------------------------------------------------------------------------
// Fallback binned-rescan edge kernel (round-2 path).
__global__ __launch_bounds__(1024) void k_edge_bin(const unsigned int* __restrict__ ei,
                                                   const float* __restrict__ x,
                                                   const int* __restrict__ flag,
                                                   float* __restrict__ part,
                                                   int E, int nchunk, int N) {
    __shared__ float acc[BINSZ * 6];
    const int bin = blockIdx.x % NBINS;
    const int chunk = blockIdx.x / NBINS;
    const int lo = bin * BINSZ;
    const int hi = (lo + BINSZ < N) ? (lo + BINSZ) : N;
    const int nloc = hi - lo;
    for (int i = threadIdx.x; i < nloc * 6; i += 1024) acc[i] = 0.0f;
    __syncthreads();

    const int is64 = *flag;
    const long long ce = ((long long)E + nchunk - 1) / nchunk;
    const long long e0 = (long long)chunk * ce;
    long long e1 = e0 + ce;
    if (e1 > E) e1 = E;

    for (long long e = e0 + threadIdx.x; e < e1; e += 1024) {
        const int d = is64 ? (int)ei[2 * ((size_t)E + (size_t)e)] : (int)ei[(size_t)E + (size_t)e];
        if (d >= lo && d < hi) {
            const int s = is64 ? (int)ei[2 * (size_t)e] : (int)ei[(size_t)e];
            const float* xr = x + (size_t)s * INC;
            float* a = acc + (d - lo) * 6;
            atomicAdd(a + 0, xr[0]);
            atomicAdd(a + 1, xr[1]);
            atomicAdd(a + 2, xr[2]);
            atomicAdd(a + 3, xr[3]);
            atomicAdd(a + 4, xr[4]);
            atomicAdd(a + 5, 1.0f);
        }
    }
    __syncthreads();
    float* o = part + (size_t)chunk * ((size_t)N * 6) + (size_t)lo * 6;
    for (int i = threadIdx.x; i < nloc * 6; i += 1024) o[i] = acc[i];
}

// ---------------------------------------------------------------------------
// Reduce partials + node update: h[n] = relu(sum_c part[c][n]/deg @ W1 + x@root1 + b1)
__global__ void k_node2(const float* __restrict__ x, const float* __restrict__ part,
                        const float* __restrict__ W1, const float* __restrict__ root1,
                        const float* __restrict__ b1, float* __restrict__ h,
                        int N, int nchunk) {
    int n = blockIdx.x * blockDim.x + threadIdx.x;
    if (n >= N) return;
    float s[6] = {0.f, 0.f, 0.f, 0.f, 0.f, 0.f};
    for (int c = 0; c < nchunk; c++) {
        const float* p = part + (size_t)c * ((size_t)N * 6) + (size_t)n * 6;
#pragma unroll
        for (int j = 0; j < 6; j++) s[j] += p[j];
    }
    const float inv = 1.0f / fmaxf(s[5], 1.0f);
    float xs[INC], xv[INC];
#pragma unroll
    for (int c = 0; c < INC; c++) {
        xs[c] = s[c] * inv;
        xv[c] = x[(size_t)n * INC + c];
    }
    float hv[H1C];
#pragma unroll
    for (int j = 0; j < H1C; j++) {
        float v = b1[j];
#pragma unroll
        for (int c = 0; c < INC; c++)
            v = fmaf(xs[c], W1[c * H1C + j], fmaf(xv[c], root1[c * H1C + j], v));
        hv[j] = fmaxf(v, 0.0f);  // relu(leaky(relu(v))) == relu(v)
    }
    float4* hp = (float4*)(h + (size_t)n * H1C);
#pragma unroll
    for (int q = 0; q < 4; q++)
        hp[q] = make_float4(hv[4 * q], hv[4 * q + 1], hv[4 * q + 2], hv[4 * q + 3]);
}

// ---------------------------------------------------------------------------
// xp_part[blk][k][j] = sum_{n in chunk} pos[n][k] * h[n][j]
__global__ __launch_bounds__(1024) void k_pool(const float* __restrict__ pos,
                                               const float* __restrict__ h,
                                               float* __restrict__ xp_part, int N, int nb) {
    __shared__ float red[KCL * (H1C + 1)];
    const int tid = threadIdx.x;
    const int k = tid & (KCL - 1);
    const int sub = tid >> 8;
    const int chunk = (N + nb - 1) / nb;
    const int n0 = blockIdx.x * chunk;
    const int n1 = min(n0 + chunk, N);

    float acc[H1C];
#pragma unroll
    for (int j = 0; j < H1C; j++) acc[j] = 0.0f;

#pragma unroll 2
    for (int n = n0 + sub; n < n1; n += 4) {
        const float p = pos[(size_t)n * KCL + k];
        const float4* hr = (const float4*)(h + (size_t)n * H1C);
        float4 h0 = hr[0], h1 = hr[1], h2 = hr[2], h3 = hr[3];
        acc[0]  = fmaf(p, h0.x, acc[0]);  acc[1]  = fmaf(p, h0.y, acc[1]);
        acc[2]  = fmaf(p, h0.z, acc[2]);  acc[3]  = fmaf(p, h0.w, acc[3]);
        acc[4]  = fmaf(p, h1.x, acc[4]);  acc[5]  = fmaf(p, h1.y, acc[5]);
        acc[6]  = fmaf(p, h1.z, acc[6]);  acc[7]  = fmaf(p, h1.w, acc[7]);
        acc[8]  = fmaf(p, h2.x, acc[8]);  acc[9]  = fmaf(p, h2.y, acc[9]);
        acc[10] = fmaf(p, h2.z, acc[10]); acc[11] = fmaf(p, h2.w, acc[11]);
        acc[12] = fmaf(p, h3.x, acc[12]); acc[13] = fmaf(p, h3.y, acc[13]);
        acc[14] = fmaf(p, h3.z, acc[14]); acc[15] = fmaf(p, h3.w, acc[15]);
    }

    for (int i = tid; i < KCL * (H1C + 1); i += 1024) red[i] = 0.0f;
    __syncthreads();
#pragma unroll
    for (int j = 0; j < H1C; j++) atomicAdd(&red[k * (H1C + 1) + j], acc[j]);
    __syncthreads();
    float* o = xp_part + (size_t)blockIdx.x * (KCL * H1C);
    for (int i = tid; i < KCL * H1C; i += 1024) {
        int kk = i >> 4, j = i & 15;
        o[i] = red[kk * (H1C + 1) + j];
    }
}

// ---------------------------------------------------------------------------
__global__ __launch_bounds__(1024) void k_xpred(const float* __restrict__ xp_part,
                                                float* __restrict__ xp, int nb) {
    __shared__ float r[1024];
    const int li = threadIdx.x & 255;
    const int sub = threadIdx.x >> 8;
    const int i = blockIdx.x * 256 + li;
    float s = 0.0f;
    for (int b = sub; b < nb; b += 4) s += xp_part[(size_t)b * (KCL * H1C) + i];
    r[threadIdx.x] = s;
    __syncthreads();
    if (threadIdx.x < 256)
        xp[blockIdx.x * 256 + threadIdx.x] =
            r[threadIdx.x] + r[256 + threadIdx.x] + r[512 + threadIdx.x] + r[768 + threadIdx.x];
}

// ---------------------------------------------------------------------------
// Tail: adj strictly positive => mask all-ones, deg2 = 256.
// Column sums via register butterfly (__shfl_xor) — NO same-address atomics.
__global__ __launch_bounds__(256) void k_tail(const float* __restrict__ xp,
                                              const float* __restrict__ W2,
                                              const float* __restrict__ root2,
                                              const float* __restrict__ b2,
                                              const float* __restrict__ lw1,
                                              const float* __restrict__ lb1,
                                              const float* __restrict__ lw2,
                                              const float* __restrict__ lb2,
                                              float* __restrict__ out) {
    __shared__ float red[4][H2C];
    __shared__ float bcast[H2C];
    const int t = threadIdx.x;     // pooled-node row, 0..255
    const int wv = t >> 6;
    const int lane = t & 63;

    float row[H1C];
#pragma unroll
    for (int c = 0; c < H1C; c++) row[c] = xp[t * H1C + c];

    // ---- stage 1: column sums of xw = xp @ W2 ----
    float v1[H2C];
#pragma unroll
    for (int j = 0; j < H2C; j++) {
        float v = 0.0f;
#pragma unroll
        for (int c = 0; c < H1C; c++) v = fmaf(row[c], W2[c * H2C + j], v);
        v1[j] = v;
    }
#pragma unroll
    for (int off = 1; off < 64; off <<= 1) {
#pragma unroll
        for (int j = 0; j < H2C; j++) v1[j] += __shfl_xor(v1[j], off);
    }
    if (lane == 0) {
#pragma unroll
        for (int j = 0; j < H2C; j++) red[wv][j] = v1[j];
    }
    __syncthreads();
    if (t < H2C) bcast[t] = red[0][t] + red[1][t] + red[2][t] + red[3][t];
    __syncthreads();

    // ---- stage 2: h2 rows + column sums for global mean ----
    float v2[H2C];
#pragma unroll
    for (int j = 0; j < H2C; j++) {
        float v = bcast[j] * (1.0f / KCL) + b2[j];
#pragma unroll
        for (int c = 0; c < H1C; c++) v = fmaf(row[c], root2[c * H2C + j], v);
        v2[j] = fmaxf(v, 0.0f);  // relu (leaky(relu(v)) == relu(v))
    }
#pragma unroll
    for (int off = 1; off < 64; off <<= 1) {
#pragma unroll
        for (int j = 0; j < H2C; j++) v2[j] += __shfl_xor(v2[j], off);
    }
    if (lane == 0) {
#pragma unroll
        for (int j = 0; j < H2C; j++) red[wv][j] = v2[j];
    }
    __syncthreads();

    if (t == 0) {
        float g[H2C];
#pragma unroll
        for (int j = 0; j < H2C; j++)
            g[j] = (red[0][j] + red[1][j] + red[2][j] + red[3][j]) * (1.0f / KCL);
        float u[8];
#pragma unroll
        for (int a = 0; a < 8; a++) {
            float v = lb1[a];
#pragma unroll
            for (int j = 0; j < H2C; j++) v = fmaf(g[j], lw1[j * 8 + a], v);
            u[a] = v > 0.0f ? v : 0.1f * v;  // leaky
        }
#pragma unroll
        for (int o = 0; o < 2; o++) {
            float v = lb2[o];
#pragma unroll
            for (int a = 0; a < 8; a++) v = fmaf(u[a], lw2[a * 2 + o], v);
            out[o] = v;
        }
    }
}

// ---------------------------------------------------------------------------
extern "C" void kernel_launch(void* const* d_in, const int* in_sizes, int n_in,
                              void* d_out, int out_size, void* d_ws, size_t ws_size,
                              hipStream_t stream) {
    const float* x         = (const float*)d_in[0];
    const unsigned int* ei = (const unsigned int*)d_in[1];
    // d_in[2] = edge_attr: unused (adj has no exact zeros -> mask all-ones)
    const float* pos   = (const float*)d_in[3];
    const float* W1    = (const float*)d_in[4];
    const float* root1 = (const float*)d_in[5];
    const float* b1    = (const float*)d_in[6];
    const float* W2    = (const float*)d_in[7];
    const float* root2 = (const float*)d_in[8];
    const float* b2    = (const float*)d_in[9];
    const float* lw1   = (const float*)d_in[10];
    const float* lb1   = (const float*)d_in[11];
    const float* lw2   = (const float*)d_in[12];
    const float* lb2   = (const float*)d_in[13];
    float* out = (float*)d_out;

    const int N = in_sizes[0] / INC;  // 100000
    const int E = in_sizes[1] / 2;    // 3200000
    const int NB = (N + PB_SZ - 1) >> PB_SHIFT;

    // common workspace prefix (floats): [xp 4096][flag 16][xp_part][h N*16]
    float* ws      = (float*)d_ws;
    float* xp      = ws;
    int*   flag    = (int*)(xp + KCL * H1C);
    float* xp_part = (float*)(flag + 16);
    float* h       = xp_part + (size_t)POOL_NB * (KCL * H1C);
    float* tail0   = h + (size_t)N * H1C;

    const size_t base_floats = (size_t)(KCL * H1C) + 16 + (size_t)POOL_NB * (KCL * H1C) + (size_t)N * H1C;
    // fast path extras: part[PB_S*N*6] + bucket[NB*PB_C] + gcur[256]
    const size_t fast_floats = base_floats + (size_t)PB_S * N * 6 + (size_t)NB * PB_C + 256;

    k_detect<<<1, 64, 0, stream>>>(ei, flag);

    if (ws_size / 4 >= fast_floats && N <= 131072 && NB <= PB_NBMAX) {
        // fast path: bucket partition + dense gather
        float* part      = tail0;
        unsigned* bucket = (unsigned*)(part + (size_t)PB_S * N * 6);
        unsigned* gcur   = bucket + (size_t)NB * PB_C;
        const int P = (E + PB_M - 1) / PB_M;

        k_init<<<1, 256, 0, stream>>>(gcur, NB);
        k_part<<<P, 1024, 0, stream>>>(ei, flag, gcur, bucket, E, NB);
        k_gather<<<NB * PB_S, 1024, 0, stream>>>(bucket, gcur, x, part, N, NB);
        k_node2<<<(N + 255) / 256, 256, 0, stream>>>(x, part, W1, root1, b1, h, N, PB_S);
    } else {
        // fallback: binned rescan with as many chunks as fit
        const size_t avail = ws_size / 4 > base_floats ? ws_size / 4 - base_floats : 0;
        int nchunk = (int)(avail / ((size_t)N * 6));
        if (nchunk > MAXCHUNK) nchunk = MAXCHUNK;
        if (nchunk < 1) nchunk = 1;
        float* part = tail0;
        k_edge_bin<<<NBINS * nchunk, 1024, 0, stream>>>(ei, x, flag, part, E, nchunk, N);
        k_node2<<<(N + 255) / 256, 256, 0, stream>>>(x, part, W1, root1, b1, h, N, nchunk);
    }
    k_pool<<<POOL_NB, 1024, 0, stream>>>(pos, h, xp_part, N, POOL_NB);
    k_xpred<<<16, 1024, 0, stream>>>(xp_part, xp, POOL_NB);
    k_tail<<<1, 256, 0, stream>>>(xp, W2, root2, b2, lw1, lb1, lw2, lb2, out);
}